// Round 9
// baseline (110.238 us; speedup 1.0000x reference)
//
#include <hip/hip_runtime.h>
#include <hip/hip_bf16.h>

// MHA with torch-faithful reshape bug: effective attention is
// B=2, H=8, Seq=2048 (= S*N_HEADS), Dh=64.
// Pipeline: [qkv_proj] -> [flash attn] -> [out_proj splitK + reduce].
// R8: attn: swapped QK^T (mfma(K,Q)) keeps P in registers; cvt_pk + 2-round
//     shfl_xor butterfly redistributes P into the PV B-fragment. Deletes the
//     P LDS round-trip; LDS 73->37KB -> 3 WG/CU.

typedef __attribute__((ext_vector_type(4))) float f32x4;
typedef __attribute__((ext_vector_type(8))) short short8;
typedef __attribute__((ext_vector_type(4))) short short4v;
typedef __attribute__((ext_vector_type(4))) unsigned int u32x4;

#define SEQ 2048      // S * N_HEADS
#define DH 64
#define BH 16         // B * H
#define ROWS 512      // B * S
#define DM 512        // d_model
#define NQ 4096       // d_model * n_heads
#define KSPLIT 8

static __device__ __forceinline__ unsigned short f2bf(float f) {
    return __builtin_bit_cast(unsigned short, __float2bfloat16(f));
}
static __device__ __forceinline__ short4v pk4(float a, float b, float c, float d) {
    return short4v{(short)f2bf(a), (short)f2bf(b), (short)f2bf(c), (short)f2bf(d)};
}
static __device__ __forceinline__ unsigned cvt_pk_bf16(float lo, float hi) {
    unsigned r;
    asm("v_cvt_pk_bf16_f32 %0, %1, %2" : "=v"(r) : "v"(lo), "v"(hi));
    return r;
}

// ---------------- Kernel 1: fused QKV projection (unchanged from R6) ----------------
__global__ __launch_bounds__(256) void qkv_proj_kernel(
    const float* __restrict__ Q, const float* __restrict__ K, const float* __restrict__ V,
    const float* __restrict__ Wq, const float* __restrict__ bq,
    const float* __restrict__ Wk, const float* __restrict__ bk,
    const float* __restrict__ Wv, const float* __restrict__ bv,
    unsigned short* __restrict__ q_bf, unsigned short* __restrict__ k_bf,
    unsigned short* __restrict__ vT_bf)
{
    const int mat = blockIdx.z;
    const float* X    = (mat == 0) ? Q  : (mat == 1) ? K  : V;
    const float* W    = (mat == 0) ? Wq : (mat == 1) ? Wk : Wv;
    const float* bias = (mat == 0) ? bq : (mat == 1) ? bk : bv;

    const int n0 = blockIdx.x * 64;
    const int m0 = blockIdx.y * 64;
    const int tid = threadIdx.x;
    const int w = tid >> 6, l = tid & 63;
    const int lr = l & 15, lg = l >> 4;

    __shared__ unsigned short a_lds[64][72];
    __shared__ unsigned short wt_lds[64 * 72];

    const int xr0 = tid >> 4, xc4 = (tid & 15) * 4;
    const int wn = tid & 63, wkseg = tid >> 6;
    const int wxr = (wn >> 3) & 7;

    f32x4 acc[4];
#pragma unroll
    for (int ct = 0; ct < 4; ++ct) acc[ct] = f32x4{0.f, 0.f, 0.f, 0.f};

    float4 rx[4];
    float rwv[16];

#pragma unroll
    for (int i = 0; i < 4; ++i)
        rx[i] = *reinterpret_cast<const float4*>(X + (m0 + i * 16 + xr0) * DM + xc4);
#pragma unroll
    for (int j = 0; j < 16; ++j)
        rwv[j] = W[(size_t)(wkseg * 16 + j) * NQ + n0 + wn];

    for (int t = 0; t < 8; ++t) {
#pragma unroll
        for (int i = 0; i < 4; ++i)
            *reinterpret_cast<short4v*>(&a_lds[i * 16 + xr0][xc4]) =
                pk4(rx[i].x, rx[i].y, rx[i].z, rx[i].w);
#pragma unroll
        for (int j4 = 0; j4 < 4; ++j4) {
            int kb = wkseg * 2 + (j4 >> 1);
            int off = wn * 72 + ((kb ^ wxr) << 3) + (j4 & 1) * 4;
            *reinterpret_cast<short4v*>(&wt_lds[off]) =
                pk4(rwv[j4 * 4 + 0], rwv[j4 * 4 + 1], rwv[j4 * 4 + 2], rwv[j4 * 4 + 3]);
        }
        __syncthreads();

        if (t < 7) {
            int k0 = (t + 1) * 64;
#pragma unroll
            for (int i = 0; i < 4; ++i)
                rx[i] = *reinterpret_cast<const float4*>(X + (m0 + i * 16 + xr0) * DM + k0 + xc4);
#pragma unroll
            for (int j = 0; j < 16; ++j)
                rwv[j] = W[(size_t)(k0 + wkseg * 16 + j) * NQ + n0 + wn];
        }

#pragma unroll
        for (int ks = 0; ks < 2; ++ks) {
            short8 a = *reinterpret_cast<const short8*>(&a_lds[w * 16 + lr][ks * 32 + lg * 8]);
#pragma unroll
            for (int ct = 0; ct < 4; ++ct) {
                int row = ct * 16 + lr;
                int kb = ks * 4 + lg;
                short8 b = *reinterpret_cast<const short8*>(
                    &wt_lds[row * 72 + ((kb ^ ((row >> 3) & 7)) << 3)]);
                acc[ct] = __builtin_amdgcn_mfma_f32_16x16x32_bf16(a, b, acc[ct], 0, 0, 0);
            }
        }
        __syncthreads();
    }

#pragma unroll
    for (int ct = 0; ct < 4; ++ct) {
        int c = n0 + ct * 16 + lr;
        float bv_ = bias[c];
        int h = (c >> 6) & 7, d = c & 63, c1 = c >> 9;
#pragma unroll
        for (int r = 0; r < 4; ++r) {
            int row = m0 + w * 16 + lg * 4 + r;   // global row = b*256 + s
            int b = row >> 8, s = row & 255;
            int n = s * 8 + c1;
            unsigned short bfv = f2bf(acc[ct][r] + bv_);
            if (mat == 0)      q_bf[((b * 8 + h) * SEQ + n) * DH + d] = bfv;
            else if (mat == 1) k_bf[((b * 8 + h) * SEQ + n) * DH + d] = bfv;
            else               vT_bf[((b * 8 + h) * DH + d) * SEQ + n] = bfv;
        }
    }
}

// ---------------- Kernel 2: flash attention, in-register P ----------------
// 512 threads = 8 waves; waves 0-3 keys [0,1024), waves 4-7 keys [1024,2048).
// Swapped QK^T: s = mfma(K_frag, Q_frag) => lane holds P[q=lr][16 keys
// {ct*16+lg*4+r}]. cvt_pk to bf16 (u32 Wp[c*2+h], keys c*16+lg*4+2h+{0,1}),
// then 2-round butterfly (xor32, xor16) lands the PV B-fragment
// pb[ks].u32[j] = keys ks*32+lg*8+2j+{0,1}. PV: o = mfma(V^T_frag, pb).
__global__ __launch_bounds__(512, 6) void attn_kernel(
    const unsigned short* __restrict__ q_bf,
    const unsigned short* __restrict__ k_bf,
    const unsigned short* __restrict__ vT_bf,
    unsigned short* __restrict__ ctx_bf)
{
    const int bh = blockIdx.y;
    const int b = bh >> 3, h = bh & 7;
    const int n0 = blockIdx.x * 64;
    const int tid = threadIdx.x;
    const int w = tid >> 6, l = tid & 63;
    const int wq = w & 3, half = w >> 2;
    const int lr = l & 15, lg = l >> 4;
    const int gtid = tid & 255;

    const unsigned short* qb = q_bf + (size_t)bh * SEQ * DH;
    const unsigned short* kb = k_bf + (size_t)bh * SEQ * DH;
    const unsigned short* vb = vT_bf + (size_t)bh * DH * SEQ;

    // K halves in kvl[0..1], V^T halves in kvl[2..3]. Epilogue o_red overlays
    // kvl[0..1] (dead after the loop's final barrier).
    __shared__ __align__(16) unsigned short kvl[4][64][72];
    __shared__ float l_red[4][16];

    const int qrow = n0 + wq * 16 + lr;
    short8 aq[2];
    aq[0] = *reinterpret_cast<const short8*>(qb + qrow * DH + lg * 8);
    aq[1] = *reinterpret_cast<const short8*>(qb + qrow * DH + 32 + lg * 8);

    f32x4 o[4];
#pragma unroll
    for (int i = 0; i < 4; ++i) o[i] = f32x4{0.f, 0.f, 0.f, 0.f};
    float l_part = 0.f;

    const int srow = gtid >> 3, sc8 = (gtid & 7) * 8;
    const int kbase0 = half * (SEQ / 2);

    short8 rk[2], rv[2];
#pragma unroll
    for (int i = 0; i < 2; ++i) {
        int row = srow + i * 32;
        rk[i] = *reinterpret_cast<const short8*>(kb + (kbase0 + row) * DH + sc8);
        rv[i] = *reinterpret_cast<const short8*>(vb + row * SEQ + kbase0 + sc8);
    }

    const bool lowc  = (lg < 2);
    const bool sendR = (lg == 0) || (lg == 3);
    const bool oddlg = (lg & 1);

    for (int kt = 0; kt < SEQ / 2 / 64; ++kt) {
#pragma unroll
        for (int i = 0; i < 2; ++i) {
            *reinterpret_cast<short8*>(&kvl[half][srow + i * 32][sc8]) = rk[i];
            *reinterpret_cast<short8*>(&kvl[2 + half][srow + i * 32][sc8]) = rv[i];
        }
        __syncthreads();

        if (kt < SEQ / 2 / 64 - 1) {
            int kb0 = kbase0 + (kt + 1) * 64;
#pragma unroll
            for (int i = 0; i < 2; ++i) {
                int row = srow + i * 32;
                rk[i] = *reinterpret_cast<const short8*>(kb + (kb0 + row) * DH + sc8);
                rv[i] = *reinterpret_cast<const short8*>(vb + row * SEQ + kb0 + sc8);
            }
        }

        // S^T = K Q^T : C[key=ct*16+lg*4+r][q=lr]
        f32x4 s[4];
#pragma unroll
        for (int ct = 0; ct < 4; ++ct) s[ct] = f32x4{0.f, 0.f, 0.f, 0.f};
#pragma unroll
        for (int ks = 0; ks < 2; ++ks) {
#pragma unroll
            for (int ct = 0; ct < 4; ++ct) {
                short8 kfrag = *reinterpret_cast<const short8*>(&kvl[half][ct * 16 + lr][ks * 32 + lg * 8]);
                s[ct] = __builtin_amdgcn_mfma_f32_16x16x32_bf16(kfrag, aq[ks], s[ct], 0, 0, 0);
            }
        }

        // p = exp(s/8) = exp2(s * 0.125*log2 e), in place; per-lane partial sum
        float rs_t = 0.f;
#pragma unroll
        for (int ct = 0; ct < 4; ++ct)
#pragma unroll
            for (int r = 0; r < 4; ++r) {
                float pv = exp2f(s[ct][r] * 0.18033688011112042f);
                s[ct][r] = pv;
                rs_t += pv;
            }
        l_part += rs_t;

        // pack: Wp[c*2+h] = bf16x2 of keys c*16+lg*4+2h+{0,1} (q=lr)
        unsigned Wp[8];
#pragma unroll
        for (int c = 0; c < 4; ++c) {
            Wp[c * 2 + 0] = cvt_pk_bf16(s[c][0], s[c][1]);
            Wp[c * 2 + 1] = cvt_pk_bf16(s[c][2], s[c][3]);
        }

        // round 1 (xor 32): lg<2 keep c in {0,2}, send c in {1,3}; lg>=2 inverse
        unsigned keepA[4], r1r[4];
#pragma unroll
        for (int a = 0; a < 2; ++a)
#pragma unroll
            for (int hh = 0; hh < 2; ++hh) {
                int i = a * 2 + hh;
                unsigned snd = lowc ? Wp[(2 * a + 1) * 2 + hh] : Wp[(2 * a) * 2 + hh];
                keepA[i]     = lowc ? Wp[(2 * a) * 2 + hh]     : Wp[(2 * a + 1) * 2 + hh];
                r1r[i] = (unsigned)__shfl_xor((int)snd, 32);
            }
        // round 2 (xor 16): lg 0,3 send the recv set; lg 1,2 send the kept set
        unsigned r2k[4], r2r[4];
#pragma unroll
        for (int i = 0; i < 4; ++i) {
            unsigned snd = sendR ? r1r[i] : keepA[i];
            r2k[i]       = sendR ? keepA[i] : r1r[i];
            r2r[i] = (unsigned)__shfl_xor((int)snd, 16);
        }

        // assemble B-fragments: pb[ks].u32[j] = key block (c=2ks+(lg>>1),
        // g = 2(lg&1)+(j>>1), h=j&1); g-low = (lg odd ? r2r : r2k)
        u32x4 pbu[2];
#pragma unroll
        for (int ks = 0; ks < 2; ++ks) {
            unsigned g0a = oddlg ? r2r[2 * ks + 0] : r2k[2 * ks + 0];
            unsigned g0b = oddlg ? r2r[2 * ks + 1] : r2k[2 * ks + 1];
            unsigned g1a = oddlg ? r2k[2 * ks + 0] : r2r[2 * ks + 0];
            unsigned g1b = oddlg ? r2k[2 * ks + 1] : r2r[2 * ks + 1];
            pbu[ks] = u32x4{g0a, g0b, g1a, g1b};
        }

        // O^T += V^T P^T : C[d=dt*16+lg*4+r][q=lr]
#pragma unroll
        for (int ks = 0; ks < 2; ++ks) {
            short8 pfrag = __builtin_bit_cast(short8, pbu[ks]);
#pragma unroll
            for (int dt = 0; dt < 4; ++dt) {
                short8 vfrag = *reinterpret_cast<const short8*>(&kvl[2 + half][dt * 16 + lr][ks * 32 + lg * 8]);
                o[dt] = __builtin_amdgcn_mfma_f32_16x16x32_bf16(vfrag, pfrag, o[dt], 0, 0, 0);
            }
        }
        __syncthreads();
    }

    // full row sum for q=lr (over all lg groups of this half)
    float rs = l_part;
    rs += __shfl_xor(rs, 16);
    rs += __shfl_xor(rs, 32);

    // merge halves; o_red overlays the dead K planes
    float* o_red = (float*)&kvl[0][0][0];          // [4][16][72] floats
    const int orow = (wq * 16 + lr) * 72;
    if (half == 1) {
#pragma unroll
        for (int dt = 0; dt < 4; ++dt)
            *reinterpret_cast<f32x4*>(&o_red[orow + dt * 16 + lg * 4]) = o[dt];
        if (lg == 0) l_red[wq][lr] = rs;
    }
    __syncthreads();
    if (half == 0) {
        float inv = 1.f / (rs + l_red[wq][lr]);
        int n = n0 + wq * 16 + lr;
        int sp = n >> 3;
        int cbase = (n & 7) * 512 + h * 64;
        unsigned short* dst = ctx_bf + (size_t)(b * 256 + sp) * NQ + cbase;
#pragma unroll
        for (int dt = 0; dt < 4; ++dt) {
            f32x4 oo = *reinterpret_cast<f32x4*>(&o_red[orow + dt * 16 + lg * 4]);
            oo = (o[dt] + oo) * inv;
            *reinterpret_cast<short4v*>(dst + dt * 16 + lg * 4) = pk4(oo[0], oo[1], oo[2], oo[3]);
        }
    }
}

// ---------------- Kernel 3: output projection, split-K (unchanged) ----------------
__global__ __launch_bounds__(256) void out_proj_splitk_kernel(
    const unsigned short* __restrict__ ctx_bf,
    const float* __restrict__ Wf,
    float* __restrict__ part)
{
    const int n0 = blockIdx.x * 64;
    const int m0 = blockIdx.y * 64;
    const int ksplit = blockIdx.z;
    const int kbase = ksplit * (NQ / KSPLIT);
    const int tid = threadIdx.x;
    const int w = tid >> 6, l = tid & 63;
    const int lr = l & 15, lg = l >> 4;

    __shared__ unsigned short a_lds[64][72];
    __shared__ unsigned short wt_lds[64 * 72];

    const int arow0 = tid >> 3, ac8 = (tid & 7) * 8;
    const int wn = tid & 63, wkseg = tid >> 6;
    const int wxr = (wn >> 3) & 7;

    f32x4 acc[4];
#pragma unroll
    for (int ct = 0; ct < 4; ++ct) acc[ct] = f32x4{0.f, 0.f, 0.f, 0.f};

    short8 ra[2];
    float rwv[16];

    {
#pragma unroll
        for (int i = 0; i < 2; ++i)
            ra[i] = *reinterpret_cast<const short8*>(
                ctx_bf + (size_t)(m0 + arow0 + i * 32) * NQ + kbase + ac8);
#pragma unroll
        for (int j = 0; j < 16; ++j)
            rwv[j] = Wf[(size_t)(kbase + wkseg * 16 + j) * DM + n0 + wn];
    }

    for (int t = 0; t < 8; ++t) {
#pragma unroll
        for (int i = 0; i < 2; ++i)
            *reinterpret_cast<short8*>(&a_lds[arow0 + i * 32][ac8]) = ra[i];
#pragma unroll
        for (int j4 = 0; j4 < 4; ++j4) {
            int kb = wkseg * 2 + (j4 >> 1);
            int off = wn * 72 + ((kb ^ wxr) << 3) + (j4 & 1) * 4;
            *reinterpret_cast<short4v*>(&wt_lds[off]) =
                pk4(rwv[j4 * 4 + 0], rwv[j4 * 4 + 1], rwv[j4 * 4 + 2], rwv[j4 * 4 + 3]);
        }
        __syncthreads();

        if (t < 7) {
            int k0 = kbase + (t + 1) * 64;
#pragma unroll
            for (int i = 0; i < 2; ++i)
                ra[i] = *reinterpret_cast<const short8*>(
                    ctx_bf + (size_t)(m0 + arow0 + i * 32) * NQ + k0 + ac8);
#pragma unroll
            for (int j = 0; j < 16; ++j)
                rwv[j] = Wf[(size_t)(k0 + wkseg * 16 + j) * DM + n0 + wn];
        }

#pragma unroll
        for (int ks = 0; ks < 2; ++ks) {
            short8 a = *reinterpret_cast<const short8*>(&a_lds[w * 16 + lr][ks * 32 + lg * 8]);
#pragma unroll
            for (int ct = 0; ct < 4; ++ct) {
                int row = ct * 16 + lr;
                int kb = ks * 4 + lg;
                short8 b = *reinterpret_cast<const short8*>(
                    &wt_lds[row * 72 + ((kb ^ ((row >> 3) & 7)) << 3)]);
                acc[ct] = __builtin_amdgcn_mfma_f32_16x16x32_bf16(a, b, acc[ct], 0, 0, 0);
            }
        }
        __syncthreads();
    }

    float* pbase = part + (size_t)ksplit * ROWS * DM;
#pragma unroll
    for (int ct = 0; ct < 4; ++ct) {
        int c = n0 + ct * 16 + lr;
#pragma unroll
        for (int r = 0; r < 4; ++r) {
            int row = m0 + w * 16 + lg * 4 + r;
            pbase[(size_t)row * DM + c] = acc[ct][r];
        }
    }
}

// ---------------- Kernel 4: split-K reduce + bias ----------------
__global__ __launch_bounds__(256) void out_reduce_kernel(
    const float* __restrict__ part, const float* __restrict__ bf_,
    float* __restrict__ out)
{
    int i4 = blockIdx.x * 256 + threadIdx.x;
    int e = i4 * 4;
    float4 acc = *reinterpret_cast<const float4*>(bf_ + (e & (DM - 1)));
#pragma unroll
    for (int ks = 0; ks < KSPLIT; ++ks) {
        float4 p = *reinterpret_cast<const float4*>(part + (size_t)ks * ROWS * DM + e);
        acc.x += p.x; acc.y += p.y; acc.z += p.z; acc.w += p.w;
    }
    *reinterpret_cast<float4*>(out + e) = acc;
}

extern "C" void kernel_launch(void* const* d_in, const int* in_sizes, int n_in,
                              void* d_out, int out_size, void* d_ws, size_t ws_size,
                              hipStream_t stream) {
    const float* Q  = (const float*)d_in[0];
    const float* K  = (const float*)d_in[1];
    const float* V  = (const float*)d_in[2];
    const float* Wq = (const float*)d_in[3];
    const float* bq = (const float*)d_in[4];
    const float* Wk = (const float*)d_in[5];
    const float* bk = (const float*)d_in[6];
    const float* Wv = (const float*)d_in[7];
    const float* bv = (const float*)d_in[8];
    const float* Wf = (const float*)d_in[9];
    const float* bf = (const float*)d_in[10];
    float* out = (float*)d_out;

    unsigned short* q_bf  = (unsigned short*)d_ws;
    unsigned short* k_bf  = q_bf + (size_t)BH * SEQ * DH;
    unsigned short* vT_bf = k_bf + (size_t)BH * SEQ * DH;
    unsigned short* ctx_bf = vT_bf + (size_t)BH * SEQ * DH;
    // split-K partials (8 MB) alias q_bf/k_bf — dead after attn_kernel.
    float* part = (float*)d_ws;

    qkv_proj_kernel<<<dim3(NQ / 64, ROWS / 64, 3), 256, 0, stream>>>(
        Q, K, V, Wq, bq, Wk, bk, Wv, bv, q_bf, k_bf, vT_bf);
    attn_kernel<<<dim3(SEQ / 64, BH), 512, 0, stream>>>(q_bf, k_bf, vT_bf, ctx_bf);
    out_proj_splitk_kernel<<<dim3(DM / 64, ROWS / 64, KSPLIT), 256, 0, stream>>>(
        ctx_bf, Wf, part);
    out_reduce_kernel<<<dim3(ROWS * DM / 4 / 256), 256, 0, stream>>>(part, bf, out);
}

// Round 10
// 87.074 us; speedup vs baseline: 1.2660x; 1.2660x over previous
//
#include <hip/hip_runtime.h>
#include <hip/hip_bf16.h>

// MHA with torch-faithful reshape bug: effective attention is
// B=2, H=8, Seq=2048 (= S*N_HEADS), Dh=64.
// Pipeline: [qkv_proj] -> [flash attn] -> [out_proj splitK + reduce].
// R8: attn: swapped QK^T (mfma(K,Q)) keeps P in registers; cvt_pk + 2-round
//     shfl_xor butterfly redistributes P into the PV B-fragment.
// R10: launch_bounds (512,6)->(512,4). R9 showed (512,6)'s ~85-VGPR cap forced
//      scratch spills (WRITE_SIZE 4->20MB, VGPR 40): occupancy knob, not dataflow,
//      was the regression.

typedef __attribute__((ext_vector_type(4))) float f32x4;
typedef __attribute__((ext_vector_type(8))) short short8;
typedef __attribute__((ext_vector_type(4))) short short4v;
typedef __attribute__((ext_vector_type(4))) unsigned int u32x4;

#define SEQ 2048      // S * N_HEADS
#define DH 64
#define BH 16         // B * H
#define ROWS 512      // B * S
#define DM 512        // d_model
#define NQ 4096       // d_model * n_heads
#define KSPLIT 8

static __device__ __forceinline__ unsigned short f2bf(float f) {
    return __builtin_bit_cast(unsigned short, __float2bfloat16(f));
}
static __device__ __forceinline__ short4v pk4(float a, float b, float c, float d) {
    return short4v{(short)f2bf(a), (short)f2bf(b), (short)f2bf(c), (short)f2bf(d)};
}
static __device__ __forceinline__ unsigned cvt_pk_bf16(float lo, float hi) {
    unsigned r;
    asm("v_cvt_pk_bf16_f32 %0, %1, %2" : "=v"(r) : "v"(lo), "v"(hi));
    return r;
}

// ---------------- Kernel 1: fused QKV projection (unchanged from R6) ----------------
__global__ __launch_bounds__(256) void qkv_proj_kernel(
    const float* __restrict__ Q, const float* __restrict__ K, const float* __restrict__ V,
    const float* __restrict__ Wq, const float* __restrict__ bq,
    const float* __restrict__ Wk, const float* __restrict__ bk,
    const float* __restrict__ Wv, const float* __restrict__ bv,
    unsigned short* __restrict__ q_bf, unsigned short* __restrict__ k_bf,
    unsigned short* __restrict__ vT_bf)
{
    const int mat = blockIdx.z;
    const float* X    = (mat == 0) ? Q  : (mat == 1) ? K  : V;
    const float* W    = (mat == 0) ? Wq : (mat == 1) ? Wk : Wv;
    const float* bias = (mat == 0) ? bq : (mat == 1) ? bk : bv;

    const int n0 = blockIdx.x * 64;
    const int m0 = blockIdx.y * 64;
    const int tid = threadIdx.x;
    const int w = tid >> 6, l = tid & 63;
    const int lr = l & 15, lg = l >> 4;

    __shared__ unsigned short a_lds[64][72];
    __shared__ unsigned short wt_lds[64 * 72];

    const int xr0 = tid >> 4, xc4 = (tid & 15) * 4;
    const int wn = tid & 63, wkseg = tid >> 6;
    const int wxr = (wn >> 3) & 7;

    f32x4 acc[4];
#pragma unroll
    for (int ct = 0; ct < 4; ++ct) acc[ct] = f32x4{0.f, 0.f, 0.f, 0.f};

    float4 rx[4];
    float rwv[16];

#pragma unroll
    for (int i = 0; i < 4; ++i)
        rx[i] = *reinterpret_cast<const float4*>(X + (m0 + i * 16 + xr0) * DM + xc4);
#pragma unroll
    for (int j = 0; j < 16; ++j)
        rwv[j] = W[(size_t)(wkseg * 16 + j) * NQ + n0 + wn];

    for (int t = 0; t < 8; ++t) {
#pragma unroll
        for (int i = 0; i < 4; ++i)
            *reinterpret_cast<short4v*>(&a_lds[i * 16 + xr0][xc4]) =
                pk4(rx[i].x, rx[i].y, rx[i].z, rx[i].w);
#pragma unroll
        for (int j4 = 0; j4 < 4; ++j4) {
            int kb = wkseg * 2 + (j4 >> 1);
            int off = wn * 72 + ((kb ^ wxr) << 3) + (j4 & 1) * 4;
            *reinterpret_cast<short4v*>(&wt_lds[off]) =
                pk4(rwv[j4 * 4 + 0], rwv[j4 * 4 + 1], rwv[j4 * 4 + 2], rwv[j4 * 4 + 3]);
        }
        __syncthreads();

        if (t < 7) {
            int k0 = (t + 1) * 64;
#pragma unroll
            for (int i = 0; i < 4; ++i)
                rx[i] = *reinterpret_cast<const float4*>(X + (m0 + i * 16 + xr0) * DM + k0 + xc4);
#pragma unroll
            for (int j = 0; j < 16; ++j)
                rwv[j] = W[(size_t)(k0 + wkseg * 16 + j) * NQ + n0 + wn];
        }

#pragma unroll
        for (int ks = 0; ks < 2; ++ks) {
            short8 a = *reinterpret_cast<const short8*>(&a_lds[w * 16 + lr][ks * 32 + lg * 8]);
#pragma unroll
            for (int ct = 0; ct < 4; ++ct) {
                int row = ct * 16 + lr;
                int kb = ks * 4 + lg;
                short8 b = *reinterpret_cast<const short8*>(
                    &wt_lds[row * 72 + ((kb ^ ((row >> 3) & 7)) << 3)]);
                acc[ct] = __builtin_amdgcn_mfma_f32_16x16x32_bf16(a, b, acc[ct], 0, 0, 0);
            }
        }
        __syncthreads();
    }

#pragma unroll
    for (int ct = 0; ct < 4; ++ct) {
        int c = n0 + ct * 16 + lr;
        float bv_ = bias[c];
        int h = (c >> 6) & 7, d = c & 63, c1 = c >> 9;
#pragma unroll
        for (int r = 0; r < 4; ++r) {
            int row = m0 + w * 16 + lg * 4 + r;   // global row = b*256 + s
            int b = row >> 8, s = row & 255;
            int n = s * 8 + c1;
            unsigned short bfv = f2bf(acc[ct][r] + bv_);
            if (mat == 0)      q_bf[((b * 8 + h) * SEQ + n) * DH + d] = bfv;
            else if (mat == 1) k_bf[((b * 8 + h) * SEQ + n) * DH + d] = bfv;
            else               vT_bf[((b * 8 + h) * DH + d) * SEQ + n] = bfv;
        }
    }
}

// ---------------- Kernel 2: flash attention, in-register P ----------------
// 512 threads = 8 waves; waves 0-3 keys [0,1024), waves 4-7 keys [1024,2048).
// Swapped QK^T: s = mfma(K_frag, Q_frag) => lane holds P[q=lr][16 keys
// {ct*16+lg*4+r}]. cvt_pk to bf16 (u32 Wp[c*2+h], keys c*16+lg*4+2h+{0,1}),
// then 2-round butterfly (xor32, xor16) lands the PV B-fragment
// pb[ks].u32[j] = keys ks*32+lg*8+2j+{0,1}. PV: o = mfma(V^T_frag, pb).
__global__ __launch_bounds__(512, 4) void attn_kernel(
    const unsigned short* __restrict__ q_bf,
    const unsigned short* __restrict__ k_bf,
    const unsigned short* __restrict__ vT_bf,
    unsigned short* __restrict__ ctx_bf)
{
    const int bh = blockIdx.y;
    const int b = bh >> 3, h = bh & 7;
    const int n0 = blockIdx.x * 64;
    const int tid = threadIdx.x;
    const int w = tid >> 6, l = tid & 63;
    const int wq = w & 3, half = w >> 2;
    const int lr = l & 15, lg = l >> 4;
    const int gtid = tid & 255;

    const unsigned short* qb = q_bf + (size_t)bh * SEQ * DH;
    const unsigned short* kb = k_bf + (size_t)bh * SEQ * DH;
    const unsigned short* vb = vT_bf + (size_t)bh * DH * SEQ;

    // K halves in kvl[0..1], V^T halves in kvl[2..3]. Epilogue o_red overlays
    // kvl[0..1] (dead after the loop's final barrier).
    __shared__ __align__(16) unsigned short kvl[4][64][72];
    __shared__ float l_red[4][16];

    const int qrow = n0 + wq * 16 + lr;
    short8 aq[2];
    aq[0] = *reinterpret_cast<const short8*>(qb + qrow * DH + lg * 8);
    aq[1] = *reinterpret_cast<const short8*>(qb + qrow * DH + 32 + lg * 8);

    f32x4 o[4];
#pragma unroll
    for (int i = 0; i < 4; ++i) o[i] = f32x4{0.f, 0.f, 0.f, 0.f};
    float l_part = 0.f;

    const int srow = gtid >> 3, sc8 = (gtid & 7) * 8;
    const int kbase0 = half * (SEQ / 2);

    short8 rk[2], rv[2];
#pragma unroll
    for (int i = 0; i < 2; ++i) {
        int row = srow + i * 32;
        rk[i] = *reinterpret_cast<const short8*>(kb + (kbase0 + row) * DH + sc8);
        rv[i] = *reinterpret_cast<const short8*>(vb + row * SEQ + kbase0 + sc8);
    }

    const bool lowc  = (lg < 2);
    const bool sendR = (lg == 0) || (lg == 3);
    const bool oddlg = (lg & 1);

    for (int kt = 0; kt < SEQ / 2 / 64; ++kt) {
#pragma unroll
        for (int i = 0; i < 2; ++i) {
            *reinterpret_cast<short8*>(&kvl[half][srow + i * 32][sc8]) = rk[i];
            *reinterpret_cast<short8*>(&kvl[2 + half][srow + i * 32][sc8]) = rv[i];
        }
        __syncthreads();

        if (kt < SEQ / 2 / 64 - 1) {
            int kb0 = kbase0 + (kt + 1) * 64;
#pragma unroll
            for (int i = 0; i < 2; ++i) {
                int row = srow + i * 32;
                rk[i] = *reinterpret_cast<const short8*>(kb + (kb0 + row) * DH + sc8);
                rv[i] = *reinterpret_cast<const short8*>(vb + row * SEQ + kb0 + sc8);
            }
        }

        // S^T = K Q^T : C[key=ct*16+lg*4+r][q=lr]
        f32x4 s[4];
#pragma unroll
        for (int ct = 0; ct < 4; ++ct) s[ct] = f32x4{0.f, 0.f, 0.f, 0.f};
#pragma unroll
        for (int ks = 0; ks < 2; ++ks) {
#pragma unroll
            for (int ct = 0; ct < 4; ++ct) {
                short8 kfrag = *reinterpret_cast<const short8*>(&kvl[half][ct * 16 + lr][ks * 32 + lg * 8]);
                s[ct] = __builtin_amdgcn_mfma_f32_16x16x32_bf16(kfrag, aq[ks], s[ct], 0, 0, 0);
            }
        }

        // p = exp(s/8) = exp2(s * 0.125*log2 e), in place; per-lane partial sum
        float rs_t = 0.f;
#pragma unroll
        for (int ct = 0; ct < 4; ++ct)
#pragma unroll
            for (int r = 0; r < 4; ++r) {
                float pv = exp2f(s[ct][r] * 0.18033688011112042f);
                s[ct][r] = pv;
                rs_t += pv;
            }
        l_part += rs_t;

        // pack: Wp[c*2+h] = bf16x2 of keys c*16+lg*4+2h+{0,1} (q=lr)
        unsigned Wp[8];
#pragma unroll
        for (int c = 0; c < 4; ++c) {
            Wp[c * 2 + 0] = cvt_pk_bf16(s[c][0], s[c][1]);
            Wp[c * 2 + 1] = cvt_pk_bf16(s[c][2], s[c][3]);
        }

        // round 1 (xor 32): lg<2 keep c in {0,2}, send c in {1,3}; lg>=2 inverse
        unsigned keepA[4], r1r[4];
#pragma unroll
        for (int a = 0; a < 2; ++a)
#pragma unroll
            for (int hh = 0; hh < 2; ++hh) {
                int i = a * 2 + hh;
                unsigned snd = lowc ? Wp[(2 * a + 1) * 2 + hh] : Wp[(2 * a) * 2 + hh];
                keepA[i]     = lowc ? Wp[(2 * a) * 2 + hh]     : Wp[(2 * a + 1) * 2 + hh];
                r1r[i] = (unsigned)__shfl_xor((int)snd, 32);
            }
        // round 2 (xor 16): lg 0,3 send the recv set; lg 1,2 send the kept set
        unsigned r2k[4], r2r[4];
#pragma unroll
        for (int i = 0; i < 4; ++i) {
            unsigned snd = sendR ? r1r[i] : keepA[i];
            r2k[i]       = sendR ? keepA[i] : r1r[i];
            r2r[i] = (unsigned)__shfl_xor((int)snd, 16);
        }

        // assemble B-fragments: pb[ks].u32[j] = key block (c=2ks+(lg>>1),
        // g = 2(lg&1)+(j>>1), h=j&1); g-low = (lg odd ? r2r : r2k)
        u32x4 pbu[2];
#pragma unroll
        for (int ks = 0; ks < 2; ++ks) {
            unsigned g0a = oddlg ? r2r[2 * ks + 0] : r2k[2 * ks + 0];
            unsigned g0b = oddlg ? r2r[2 * ks + 1] : r2k[2 * ks + 1];
            unsigned g1a = oddlg ? r2k[2 * ks + 0] : r2r[2 * ks + 0];
            unsigned g1b = oddlg ? r2k[2 * ks + 1] : r2r[2 * ks + 1];
            pbu[ks] = u32x4{g0a, g0b, g1a, g1b};
        }

        // O^T += V^T P^T : C[d=dt*16+lg*4+r][q=lr]
#pragma unroll
        for (int ks = 0; ks < 2; ++ks) {
            short8 pfrag = __builtin_bit_cast(short8, pbu[ks]);
#pragma unroll
            for (int dt = 0; dt < 4; ++dt) {
                short8 vfrag = *reinterpret_cast<const short8*>(&kvl[2 + half][dt * 16 + lr][ks * 32 + lg * 8]);
                o[dt] = __builtin_amdgcn_mfma_f32_16x16x32_bf16(vfrag, pfrag, o[dt], 0, 0, 0);
            }
        }
        __syncthreads();
    }

    // full row sum for q=lr (over all lg groups of this half)
    float rs = l_part;
    rs += __shfl_xor(rs, 16);
    rs += __shfl_xor(rs, 32);

    // merge halves; o_red overlays the dead K planes
    float* o_red = (float*)&kvl[0][0][0];          // [4][16][72] floats
    const int orow = (wq * 16 + lr) * 72;
    if (half == 1) {
#pragma unroll
        for (int dt = 0; dt < 4; ++dt)
            *reinterpret_cast<f32x4*>(&o_red[orow + dt * 16 + lg * 4]) = o[dt];
        if (lg == 0) l_red[wq][lr] = rs;
    }
    __syncthreads();
    if (half == 0) {
        float inv = 1.f / (rs + l_red[wq][lr]);
        int n = n0 + wq * 16 + lr;
        int sp = n >> 3;
        int cbase = (n & 7) * 512 + h * 64;
        unsigned short* dst = ctx_bf + (size_t)(b * 256 + sp) * NQ + cbase;
#pragma unroll
        for (int dt = 0; dt < 4; ++dt) {
            f32x4 oo = *reinterpret_cast<f32x4*>(&o_red[orow + dt * 16 + lg * 4]);
            oo = (o[dt] + oo) * inv;
            *reinterpret_cast<short4v*>(dst + dt * 16 + lg * 4) = pk4(oo[0], oo[1], oo[2], oo[3]);
        }
    }
}

// ---------------- Kernel 3: output projection, split-K (unchanged) ----------------
__global__ __launch_bounds__(256) void out_proj_splitk_kernel(
    const unsigned short* __restrict__ ctx_bf,
    const float* __restrict__ Wf,
    float* __restrict__ part)
{
    const int n0 = blockIdx.x * 64;
    const int m0 = blockIdx.y * 64;
    const int ksplit = blockIdx.z;
    const int kbase = ksplit * (NQ / KSPLIT);
    const int tid = threadIdx.x;
    const int w = tid >> 6, l = tid & 63;
    const int lr = l & 15, lg = l >> 4;

    __shared__ unsigned short a_lds[64][72];
    __shared__ unsigned short wt_lds[64 * 72];

    const int arow0 = tid >> 3, ac8 = (tid & 7) * 8;
    const int wn = tid & 63, wkseg = tid >> 6;
    const int wxr = (wn >> 3) & 7;

    f32x4 acc[4];
#pragma unroll
    for (int ct = 0; ct < 4; ++ct) acc[ct] = f32x4{0.f, 0.f, 0.f, 0.f};

    short8 ra[2];
    float rwv[16];

    {
#pragma unroll
        for (int i = 0; i < 2; ++i)
            ra[i] = *reinterpret_cast<const short8*>(
                ctx_bf + (size_t)(m0 + arow0 + i * 32) * NQ + kbase + ac8);
#pragma unroll
        for (int j = 0; j < 16; ++j)
            rwv[j] = Wf[(size_t)(kbase + wkseg * 16 + j) * DM + n0 + wn];
    }

    for (int t = 0; t < 8; ++t) {
#pragma unroll
        for (int i = 0; i < 2; ++i)
            *reinterpret_cast<short8*>(&a_lds[arow0 + i * 32][ac8]) = ra[i];
#pragma unroll
        for (int j4 = 0; j4 < 4; ++j4) {
            int kb = wkseg * 2 + (j4 >> 1);
            int off = wn * 72 + ((kb ^ wxr) << 3) + (j4 & 1) * 4;
            *reinterpret_cast<short4v*>(&wt_lds[off]) =
                pk4(rwv[j4 * 4 + 0], rwv[j4 * 4 + 1], rwv[j4 * 4 + 2], rwv[j4 * 4 + 3]);
        }
        __syncthreads();

        if (t < 7) {
            int k0 = kbase + (t + 1) * 64;
#pragma unroll
            for (int i = 0; i < 2; ++i)
                ra[i] = *reinterpret_cast<const short8*>(
                    ctx_bf + (size_t)(m0 + arow0 + i * 32) * NQ + k0 + ac8);
#pragma unroll
            for (int j = 0; j < 16; ++j)
                rwv[j] = Wf[(size_t)(k0 + wkseg * 16 + j) * DM + n0 + wn];
        }

#pragma unroll
        for (int ks = 0; ks < 2; ++ks) {
            short8 a = *reinterpret_cast<const short8*>(&a_lds[w * 16 + lr][ks * 32 + lg * 8]);
#pragma unroll
            for (int ct = 0; ct < 4; ++ct) {
                int row = ct * 16 + lr;
                int kb = ks * 4 + lg;
                short8 b = *reinterpret_cast<const short8*>(
                    &wt_lds[row * 72 + ((kb ^ ((row >> 3) & 7)) << 3)]);
                acc[ct] = __builtin_amdgcn_mfma_f32_16x16x32_bf16(a, b, acc[ct], 0, 0, 0);
            }
        }
        __syncthreads();
    }

    float* pbase = part + (size_t)ksplit * ROWS * DM;
#pragma unroll
    for (int ct = 0; ct < 4; ++ct) {
        int c = n0 + ct * 16 + lr;
#pragma unroll
        for (int r = 0; r < 4; ++r) {
            int row = m0 + w * 16 + lg * 4 + r;
            pbase[(size_t)row * DM + c] = acc[ct][r];
        }
    }
}

// ---------------- Kernel 4: split-K reduce + bias ----------------
__global__ __launch_bounds__(256) void out_reduce_kernel(
    const float* __restrict__ part, const float* __restrict__ bf_,
    float* __restrict__ out)
{
    int i4 = blockIdx.x * 256 + threadIdx.x;
    int e = i4 * 4;
    float4 acc = *reinterpret_cast<const float4*>(bf_ + (e & (DM - 1)));
#pragma unroll
    for (int ks = 0; ks < KSPLIT; ++ks) {
        float4 p = *reinterpret_cast<const float4*>(part + (size_t)ks * ROWS * DM + e);
        acc.x += p.x; acc.y += p.y; acc.z += p.z; acc.w += p.w;
    }
    *reinterpret_cast<float4*>(out + e) = acc;
}

extern "C" void kernel_launch(void* const* d_in, const int* in_sizes, int n_in,
                              void* d_out, int out_size, void* d_ws, size_t ws_size,
                              hipStream_t stream) {
    const float* Q  = (const float*)d_in[0];
    const float* K  = (const float*)d_in[1];
    const float* V  = (const float*)d_in[2];
    const float* Wq = (const float*)d_in[3];
    const float* bq = (const float*)d_in[4];
    const float* Wk = (const float*)d_in[5];
    const float* bk = (const float*)d_in[6];
    const float* Wv = (const float*)d_in[7];
    const float* bv = (const float*)d_in[8];
    const float* Wf = (const float*)d_in[9];
    const float* bf = (const float*)d_in[10];
    float* out = (float*)d_out;

    unsigned short* q_bf  = (unsigned short*)d_ws;
    unsigned short* k_bf  = q_bf + (size_t)BH * SEQ * DH;
    unsigned short* vT_bf = k_bf + (size_t)BH * SEQ * DH;
    unsigned short* ctx_bf = vT_bf + (size_t)BH * SEQ * DH;
    // split-K partials (8 MB) alias q_bf/k_bf — dead after attn_kernel.
    float* part = (float*)d_ws;

    qkv_proj_kernel<<<dim3(NQ / 64, ROWS / 64, 3), 256, 0, stream>>>(
        Q, K, V, Wq, bq, Wk, bk, Wv, bv, q_bf, k_bf, vT_bf);
    attn_kernel<<<dim3(SEQ / 64, BH), 512, 0, stream>>>(q_bf, k_bf, vT_bf, ctx_bf);
    out_proj_splitk_kernel<<<dim3(DM / 64, ROWS / 64, KSPLIT), 256, 0, stream>>>(
        ctx_bf, Wf, part);
    out_reduce_kernel<<<dim3(ROWS * DM / 4 / 256), 256, 0, stream>>>(part, bf, out);
}